// Round 8
// baseline (515.631 us; speedup 1.0000x reference)
//
#include <hip/hip_runtime.h>

// PointerNet: B=4, N=128, H=512, d_pair=256.
// Interface (verified):
//   inputs  f32, setup_inputs dict order
//   d_out   f32, 50,724,864 elements = [4][128][128][774]
// Per mlp g in {future(Wf1,Wf2,w3), hist1(Wh1a,Wh1b,wl1), hist2(Wh2a,Wh2b,wl2)}:
//   uv[m][c'] = sum_h P[m][h] * W1[(c'>=1024?512:0)+h][c'&1023]     (m = b*128+i)
//   y[bi,j,n] = relu( sum_k relu(u[bi][k] + v[bj][k]) * W2[k][n] )
//   p = softmax_c( sum_n y[n] * w3[n][c] )
//   out[((bi)*128+j)*774 + g*258 + {n | 256+c}] = {y | p}
//
// R16 changes (R15 measured: pair 312us serialized at ~7800 cyc/kt: MFMA 3072
// + B-LDS 3000 + VALU + v-L2, barrier-phased):
//   * 2-PRODUCT scheme: z single truncated bf16, W2 exact hi+lo split ->
//     acc = zhi@whi + zhi@wlo. Added error delta_z*w ~ max 0.007 << 0.0778
//     threshold (0.0156 floor is the harness bf16-ref quantization, seen
//     identically on the pure-f32 path). MFMA 24->16/kt/wave (2048 cyc/SIMD),
//     make_frag loses the lo half (~20 ops).
//   * wave tile 32jx128n -> 64jx64n (2 jh x 4 nq): B frag feeds 2 m-tiles ->
//     B-LDS traffic halved to 128 KB/CU/kt. z redundancy 4 now affordable.
//   * v loads issued BEFORE the B global_load_lds prefetch each body, so the
//     v wait is a counted vmcnt(8), not a drain of the in-flight B transfer.
// stage1 / prep / W2F / vF layouts and kernels: UNCHANGED from R15.
//
// Workspace (fused tier, ws>=27MiB):
//   uF_all  f32 [3][512][1024]   6 MiB @0     (u half, row-major)
//   vF_all  f32 [3][524288]      6 MiB @6M    (v half, 32x32 fragment-major)
//   w2f_all u16 [3][524288]      3 MiB @12M   (32x32 B-frag layout, hi/lo)
//   w1f_all u16 [3][2M]         12 MiB @15M   (16x16 B-frag layout, stage1)
// Fallback (<27MiB): all-VALU path + head_kernel.

typedef __attribute__((ext_vector_type(4))) float floatx4;
typedef __attribute__((ext_vector_type(2))) float floatx2;
typedef __attribute__((ext_vector_type(16))) float floatx16;
typedef __attribute__((ext_vector_type(8))) short short8;

#define KT 16
#define LSTRIDE 68  // 64 + 4 pad (LDS bank-conflict break)
#define MB (1u << 20)

__device__ __forceinline__ void gload_lds16(const void* g, void* l) {
  __builtin_amdgcn_global_load_lds(
      (const __attribute__((address_space(1))) void*)g,
      (__attribute__((address_space(3))) void*)l, 16, 0, 0);
}

// Split 8 f32 into bf16 hi (truncated) + bf16 lo (exact remainder, truncated).
__device__ __forceinline__ void split8(const float* x, short8& hi, short8& lo) {
  unsigned hb[8], lb[8];
#pragma unroll
  for (int e = 0; e < 8; e++) {
    unsigned xb = __float_as_uint(x[e]);
    unsigned h = xb & 0xFFFF0000u;
    float l = x[e] - __uint_as_float(h);    // exact
    hb[e] = h;
    lb[e] = __float_as_uint(l) & 0xFFFF0000u;
  }
  union U { unsigned u[4]; short8 s; };
  U H, L;
#pragma unroll
  for (int p = 0; p < 4; p++) {
    H.u[p] = __builtin_amdgcn_perm(hb[2 * p + 1], hb[2 * p], 0x07060302u);
    L.u[p] = __builtin_amdgcn_perm(lb[2 * p + 1], lb[2 * p], 0x07060302u);
  }
  hi = H.s;
  lo = L.s;
}

// z = relu(u + v) for 8 k-slots, truncated-bf16 hi only (2-product scheme).
__device__ __forceinline__ short8 frag_hi(
    const floatx4& ua, const floatx4& ub,
    const floatx4& va, const floatx4& vb) {
  unsigned zb[8];
#pragma unroll
  for (int e = 0; e < 4; e++) {
    float z0 = fmaxf(ua[e] + va[e], 0.0f);
    float z1 = fmaxf(ub[e] + vb[e], 0.0f);
    zb[e] = __float_as_uint(z0);
    zb[4 + e] = __float_as_uint(z1);
  }
  union U { unsigned u[4]; short8 s; } H;
#pragma unroll
  for (int p = 0; p < 4; p++)
    H.u[p] = __builtin_amdgcn_perm(zb[2 * p + 1], zb[2 * p], 0x07060302u);
  return H.s;
}

// ---------------------------------------------------------------------------
// prep: W1 -> 16x16 B-frag layout (stage1);  W2 -> 32x32 B-frag layout (pair).
// W1F[kt(16)][NF(128)][hl(2)][lane(64)][e(8)]; lane = 16g + c holds
//   W1X[kt*32 + g*8 + e][NF*16 + c]  (u/v row split baked in).
// W2F[kt(32)][nf32(8)][hl(2)][ksub(2)][lane(64)][e(8)]; lane = 32g2 + c32
//   holds W2[kt*32 + ksub*16 + g2*8 + e][nf32*32 + c32].
// ---------------------------------------------------------------------------
__device__ __forceinline__ void prep_w1_body(
    int t, const float* __restrict__ W1, unsigned short* __restrict__ W1F) {
  int lane = t & 63;
  int nf = (t >> 6) & 127;
  int kt = t >> 13;                        // 0..15
  int g = lane >> 4, c = lane & 15;
  int n = nf * 16 + c;                     // 0..2047
  int kbase = kt * 32 + g * 8;
  const float* src = W1 + (long)((n >= 1024 ? 512 : 0) + kbase) * 1024 + (n & 1023);

  unsigned hb[8], lb[8];
#pragma unroll
  for (int e = 0; e < 8; e++) {
    float w = src[(long)e * 1024];
    unsigned wb = __float_as_uint(w);
    unsigned h = wb & 0xFFFF0000u;
    float l = w - __uint_as_float(h);
    hb[e] = h;
    lb[e] = __float_as_uint(l) & 0xFFFF0000u;
  }
  union U { unsigned u[4]; short8 s; };
  U H, L;
#pragma unroll
  for (int p = 0; p < 4; p++) {
    H.u[p] = __builtin_amdgcn_perm(hb[2 * p + 1], hb[2 * p], 0x07060302u);
    L.u[p] = __builtin_amdgcn_perm(lb[2 * p + 1], lb[2 * p], 0x07060302u);
  }
  long base = ((long)kt * 128 + nf) * 2 * 64 + lane;
  *(short8*)(W1F + (base + 0) * 8) = H.s;
  *(short8*)(W1F + (base + 64) * 8) = L.s;
}

__device__ __forceinline__ void prep_w2_body32(
    int t, const float* __restrict__ W2, unsigned short* __restrict__ W2F) {
  int lane = t & 63;
  int ksub = (t >> 6) & 1;
  int nf32 = (t >> 7) & 7;
  int kt = t >> 10;                        // 0..31
  int g2 = lane >> 5, c32 = lane & 31;
  int n = nf32 * 32 + c32;
  int kbase = kt * 32 + ksub * 16 + g2 * 8;

  unsigned hb[8], lb[8];
#pragma unroll
  for (int e = 0; e < 8; e++) {
    float w = W2[(long)(kbase + e) * 256 + n];
    unsigned wb = __float_as_uint(w);
    unsigned h = wb & 0xFFFF0000u;
    float l = w - __uint_as_float(h);
    hb[e] = h;
    lb[e] = __float_as_uint(l) & 0xFFFF0000u;
  }
  union U { unsigned u[4]; short8 s; };
  U H, L;
#pragma unroll
  for (int p = 0; p < 4; p++) {
    H.u[p] = __builtin_amdgcn_perm(hb[2 * p + 1], hb[2 * p], 0x07060302u);
    L.u[p] = __builtin_amdgcn_perm(lb[2 * p + 1], lb[2 * p], 0x07060302u);
  }
  // hl=0 at base, hl=1 at base + 2*64 lanes
  long base = ((((long)kt * 8 + nf32) * 2) * 2 + ksub) * 64 + lane;
  *(short8*)(W2F + (base + 0) * 8) = H.s;
  *(short8*)(W2F + (base + 128) * 8) = L.s;
}

// Fused prep: all 3 W1 (blocks 0..1535) + all 3 W2 (blocks 1536..1919).
__global__ __launch_bounds__(256) void prep_all(
    const float* __restrict__ Wf1, const float* __restrict__ Wh1a,
    const float* __restrict__ Wh2a, const float* __restrict__ Wf2,
    const float* __restrict__ Wh1b, const float* __restrict__ Wh2b,
    unsigned short* __restrict__ w1f_all, unsigned short* __restrict__ w2f_all) {
  int bx = blockIdx.x;
  if (bx < 1536) {
    int mlp = bx >> 9;
    const float* W1 = (mlp == 0) ? Wf1 : (mlp == 1) ? Wh1a : Wh2a;
    prep_w1_body((bx & 511) * 256 + threadIdx.x, W1,
                 w1f_all + (long)mlp * (2 * MB));   // 4 MiB = 2M shorts
  } else {
    int bb = bx - 1536;                             // 0..383
    int mlp = bb >> 7;
    const float* W2 = (mlp == 0) ? Wf2 : (mlp == 1) ? Wh1b : Wh2b;
    prep_w2_body32((bb & 127) * 256 + threadIdx.x, W2,
                   w2f_all + (long)mlp * (MB / 2)); // 1 MiB = 512K shorts
  }
}

// ---------------------------------------------------------------------------
// stage1 core: split-bf16 16x16x32 MFMA; writes uF (row-major) and vF
// (32x32 A-frag-major).  bx in [0,512) = 32 mblk(16 rows) x 16 nblk(128 n).
// vF flat: ((b*32+kt)*4 + jf32)*1024 + (kg*32 + (j&31))*16 + ksub*8 + e
//   holds v[b*128 + jf32*32 + (j&31)][kt*32 + ksub*16 + kg*8 + e].
// ---------------------------------------------------------------------------
__device__ __forceinline__ void stage1_core(
    int bx, const float* __restrict__ P,
    const unsigned short* __restrict__ W1F,
    float* __restrict__ uF, float* __restrict__ vF) {
  int m0 = (bx >> 4) * 16;
  int n0 = (bx & 15) * 128;
  int tid = threadIdx.x;
  int wid = tid >> 6, lane = tid & 63;
  int g = lane >> 4, r = lane & 15;
  int nw0 = n0 + wid * 32;                 // wave covers 2 n-frags

  const float* prow = P + (long)(m0 + r) * 512;

  floatx4 acc[2];
#pragma unroll
  for (int nf = 0; nf < 2; nf++) acc[nf] = (floatx4){0.f, 0.f, 0.f, 0.f};

  for (int kt = 0; kt < 16; kt++) {
    int k0 = kt * 32 + g * 8;
    float a[8];
    floatx4 a0 = *(const floatx4*)(prow + k0);
    floatx4 a1 = *(const floatx4*)(prow + k0 + 4);
#pragma unroll
    for (int e = 0; e < 4; e++) { a[e] = a0[e]; a[4 + e] = a1[e]; }
    short8 ahi, alo;
    split8(a, ahi, alo);
#pragma unroll
    for (int nf = 0; nf < 2; nf++) {
      int nfg = (nw0 >> 4) + nf;
      const unsigned short* wp = W1F + (((long)kt * 128 + nfg) * 2 * 64 + lane) * 8;
      short8 whi = *(const short8*)wp;
      short8 wlo = *(const short8*)(wp + 64 * 8);
      acc[nf] = __builtin_amdgcn_mfma_f32_16x16x32_bf16(ahi, whi, acc[nf], 0, 0, 0);
      acc[nf] = __builtin_amdgcn_mfma_f32_16x16x32_bf16(alo, whi, acc[nf], 0, 0, 0);
      acc[nf] = __builtin_amdgcn_mfma_f32_16x16x32_bf16(ahi, wlo, acc[nf], 0, 0, 0);
    }
  }
  // D: row = g*4 + reg (m within 16-tile), col = r (n within nf 16-tile)
  if (n0 < 1024) {
    // u half -> row-major uF[m][k]
#pragma unroll
    for (int nf = 0; nf < 2; nf++)
#pragma unroll
      for (int reg = 0; reg < 4; reg++)
        uF[(long)(m0 + g * 4 + reg) * 1024 + nw0 + nf * 16 + r] = acc[nf][reg];
  } else {
    // v half -> 32x32 fragment-major vF.  value = v[m][kt*32 + nf*16 + r]
    int kt = (nw0 - 1024) >> 5;            // wave-uniform
#pragma unroll
    for (int nf = 0; nf < 2; nf++) {
#pragma unroll
      for (int reg = 0; reg < 4; reg++) {
        int m = m0 + g * 4 + reg;
        int b = m >> 7;
        int jf = (m >> 5) & 3;
        long idx = (((long)(b * 32 + kt)) * 4 + jf) * 1024 +
                   ((r >> 3) * 32 + (m & 31)) * 16 + nf * 8 + (r & 7);
        vF[idx] = acc[nf][reg];
      }
    }
  }
}

__global__ __launch_bounds__(256) void stage1_mfma3(
    const float* __restrict__ P, const unsigned short* __restrict__ w1f_all,
    float* __restrict__ uF_all, float* __restrict__ vF_all) {
  int mlp = blockIdx.x >> 9;
  stage1_core(blockIdx.x & 511, P, w1f_all + (long)mlp * (2 * MB),
              uF_all + (long)mlp * 524288, vF_all + (long)mlp * 524288);
}

// ---------------------------------------------------------------------------
// pair kernel: 2-product 32x32x16 MFMA (zhi@whi + zhi@wlo).  512 thr = 8
// waves; wave (jh = wid>>2: 64 j rows = 2 m-tiles, nq = wid&3: 64 n = 2 nf).
// Per kt: v loads (issued FIRST -> counted vmcnt wait), B prefetch via
// global_load_lds (2x32KB dbuf), u from LDS, 4 frag_hi, 16 MFMA.  Head fused.
// acc[2][2] x f32x16 = 64 VGPR.
// ---------------------------------------------------------------------------
#define PAIR_BODY(KTC, RBUF, SBUF)                                            \
  {                                                                           \
    const float* vp0 = vbase0 + (long)(KTC) * 4096;                           \
    const float* vp1 = vbase1 + (long)(KTC) * 4096;                           \
    floatx4 va0 = *(const floatx4*)(vp0);                                     \
    floatx4 va1 = *(const floatx4*)(vp0 + 4);                                 \
    floatx4 va2 = *(const floatx4*)(vp0 + 8);                                 \
    floatx4 va3 = *(const floatx4*)(vp0 + 12);                                \
    floatx4 vb0 = *(const floatx4*)(vp1);                                     \
    floatx4 vb1 = *(const floatx4*)(vp1 + 4);                                 \
    floatx4 vb2 = *(const floatx4*)(vp1 + 8);                                 \
    floatx4 vb3 = *(const floatx4*)(vp1 + 12);                                \
    const unsigned short* gs = W2F + (long)((KTC) + 1) * 16384;               \
    _Pragma("unroll")                                                         \
    for (int i = 0; i < 4; i++)                                               \
      gload_lds16(gs + (i * 512 + tid) * 8, &(SBUF)[(i * 512 + tid) * 8]);    \
    floatx4 u0 = *(const floatx4*)&ulds[(KTC) * 32 + g2 * 8];                 \
    floatx4 u1 = *(const floatx4*)&ulds[(KTC) * 32 + g2 * 8 + 4];             \
    floatx4 u2 = *(const floatx4*)&ulds[(KTC) * 32 + 16 + g2 * 8];            \
    floatx4 u3 = *(const floatx4*)&ulds[(KTC) * 32 + 16 + g2 * 8 + 4];        \
    short8 a00 = frag_hi(u0, u1, va0, va1);   /* m-tile 0, ksub 0 */          \
    short8 a01 = frag_hi(u2, u3, va2, va3);   /* m-tile 0, ksub 1 */          \
    short8 a10 = frag_hi(u0, u1, vb0, vb1);   /* m-tile 1, ksub 0 */          \
    short8 a11 = frag_hi(u2, u3, vb2, vb3);   /* m-tile 1, ksub 1 */          \
    __builtin_amdgcn_s_setprio(1);                                            \
    _Pragma("unroll")                                                         \
    for (int nf = 0; nf < 2; nf++) {                                          \
      const unsigned short* wp = (RBUF) + ((nq * 2 + nf) * 4) * 512 + lane * 8; \
      short8 whi0 = *(const short8*)wp;                                       \
      short8 whi1 = *(const short8*)(wp + 512);                               \
      short8 wlo0 = *(const short8*)(wp + 1024);                              \
      short8 wlo1 = *(const short8*)(wp + 1536);                              \
      acc[0][nf] = __builtin_amdgcn_mfma_f32_32x32x16_bf16(a00, whi0, acc[0][nf], 0, 0, 0); \
      acc[1][nf] = __builtin_amdgcn_mfma_f32_32x32x16_bf16(a10, whi0, acc[1][nf], 0, 0, 0); \
      acc[0][nf] = __builtin_amdgcn_mfma_f32_32x32x16_bf16(a01, whi1, acc[0][nf], 0, 0, 0); \
      acc[1][nf] = __builtin_amdgcn_mfma_f32_32x32x16_bf16(a11, whi1, acc[1][nf], 0, 0, 0); \
      acc[0][nf] = __builtin_amdgcn_mfma_f32_32x32x16_bf16(a00, wlo0, acc[0][nf], 0, 0, 0); \
      acc[1][nf] = __builtin_amdgcn_mfma_f32_32x32x16_bf16(a10, wlo0, acc[1][nf], 0, 0, 0); \
      acc[0][nf] = __builtin_amdgcn_mfma_f32_32x32x16_bf16(a01, wlo1, acc[0][nf], 0, 0, 0); \
      acc[1][nf] = __builtin_amdgcn_mfma_f32_32x32x16_bf16(a11, wlo1, acc[1][nf], 0, 0, 0); \
    }                                                                         \
    __builtin_amdgcn_s_setprio(0);                                            \
    __syncthreads();                                                          \
  }

__global__ __launch_bounds__(512, 4) void pair_mfma3(
    const float* __restrict__ uF_all, const float* __restrict__ vF_all,
    const unsigned short* __restrict__ w2f_all,
    const float* __restrict__ w3_0, const float* __restrict__ w3_1,
    const float* __restrict__ w3_2, float* __restrict__ out) {
  __shared__ unsigned short wbuf[2][16384];   // 2 x 32 KB B double buffer
  __shared__ float ulds[1024];                // u row (4 KB); ps scratch later
  int orig = blockIdx.x;                      // 1536 = 8 XCD * 192
  int id = (orig & 7) * 192 + (orig >> 3);    // bijective XCD swizzle
  int mlp = id >> 9;
  int bi = id & 511;
  int b = bi >> 7;
  const float* w3 = (mlp == 0) ? w3_0 : (mlp == 1) ? w3_1 : w3_2;
  const float* uF = uF_all + (long)mlp * 524288;
  const float* vF = vF_all + (long)mlp * 524288;
  const unsigned short* W2F = w2f_all + (long)mlp * 524288;

  int tid = threadIdx.x;
  int wid = tid >> 6;           // 0..7
  int lane = tid & 63;
  int jh = wid >> 2;            // j-half: rows [jh*64, +64) = m-tiles jh*2, jh*2+1
  int nq = wid & 3;             // n-quarter: cols [nq*64, +64) = nf32 nq*2, nq*2+1
  int g2 = lane >> 5;           // k-group within frag
  int c32 = lane & 31;          // row (A) / col (B/D) within 32-tile

  // v bases for the two m-tiles (jf = jh*2 + mm); per-kt stride 4096 floats.
  const float* vbase0 = vF + ((long)b * 128 + jh * 2 + 0) * 1024 + lane * 16;
  const float* vbase1 = vF + ((long)b * 128 + jh * 2 + 1) * 1024 + lane * 16;

  // Prologue: stage u row (4KB) + B slice kt=0.
  const float* urow = uF + (long)bi * 1024;
  if (tid < 256) gload_lds16(urow + tid * 4, &ulds[tid * 4]);
#pragma unroll
  for (int i = 0; i < 4; i++)
    gload_lds16(W2F + (i * 512 + tid) * 8, &wbuf[0][(i * 512 + tid) * 8]);

  floatx16 acc[2][2];
#pragma unroll
  for (int mm = 0; mm < 2; mm++)
#pragma unroll
    for (int nf = 0; nf < 2; nf++)
#pragma unroll
      for (int e = 0; e < 16; e++) acc[mm][nf][e] = 0.f;

  __syncthreads();   // u + B slice 0 resident

  for (int kt = 0; kt < 32; kt += 2) {
    PAIR_BODY(kt, wbuf[1] - 16384, wbuf[1]);        // read buf0, stage buf1
    PAIR_BODY(kt + 1, wbuf[1], wbuf[1] - 16384);    // read buf1, stage buf0
  }

  // Epilogue: D col = c32 (n), row = (reg&3) + 8*(reg>>2) + 4*g2 (j within
  // 32-tile).  y stores + fused head: reduce over c32, psum via ulds scratch.
  float* ps = ulds;   // 128 rows x 4 nq x 2 = 1024 floats (u data dead)
  float* ob = out + (long)(bi * 128) * 774 + mlp * 258;
  floatx2 w3v[2];
#pragma unroll
  for (int nf = 0; nf < 2; nf++)
    w3v[nf] = *(const floatx2*)(w3 + (nq * 64 + nf * 32 + c32) * 2);
#pragma unroll
  for (int mm = 0; mm < 2; mm++) {
#pragma unroll
    for (int reg = 0; reg < 16; reg++) {
      int row = jh * 64 + mm * 32 + (reg & 3) + 8 * (reg >> 2) + 4 * g2;
      float* orow = ob + (long)row * 774 + nq * 64 + c32;
      float s0 = 0.f, s1 = 0.f;
#pragma unroll
      for (int nf = 0; nf < 2; nf++) {
        float y = acc[mm][nf][reg];
        y = y > 0.f ? y : 0.f;
        orow[nf * 32] = y;
        s0 += y * w3v[nf][0];
        s1 += y * w3v[nf][1];
      }
#pragma unroll
      for (int off = 1; off < 32; off <<= 1) {
        s0 += __shfl_xor(s0, off, 64);
        s1 += __shfl_xor(s1, off, 64);
      }
      if (c32 == 0) {
        ps[row * 8 + nq * 2 + 0] = s0;
        ps[row * 8 + nq * 2 + 1] = s1;
      }
    }
  }
  __syncthreads();
  if (tid < 128) {
    int row = tid;
    float s0 = ps[row * 8 + 0] + ps[row * 8 + 2] + ps[row * 8 + 4] + ps[row * 8 + 6];
    float s1 = ps[row * 8 + 1] + ps[row * 8 + 3] + ps[row * 8 + 5] + ps[row * 8 + 7];
    float m = fmaxf(s0, s1);
    float e0 = __expf(s0 - m), e1 = __expf(s1 - m);
    float inv = 1.0f / (e0 + e1);
    floatx2 pr;
    pr[0] = e0 * inv;
    pr[1] = e1 * inv;
    *(floatx2*)(ob + (long)row * 774 + 256) = pr;   // 8B aligned
  }
}

// ---------------------------------------------------------------------------
// VALU fallback path (proven; used only if ws < 27 MiB). uv row-major 4 MiB.
// ---------------------------------------------------------------------------
__global__ __launch_bounds__(256) void stage1_valu(
    const float* __restrict__ P, const float* __restrict__ W1,
    float* __restrict__ uv) {
  __shared__ float at[KT][LSTRIDE];
  __shared__ float wt[KT][LSTRIDE];
  int bx = blockIdx.x;
  int m0 = (bx >> 5) * 64;
  int c0 = (bx & 31) * 64;
  int half = c0 >> 10;
  int ccol = c0 & 1023;
  int tid = threadIdx.x;
  int tm = tid >> 4, tn = tid & 15;
  int lm = tid >> 2;
  int lk4 = (tid & 3) * 4;
  int lkk = tid >> 4;
  int lc4 = (tid & 15) * 4;

  float acc[4][4] = {};

  for (int k0 = 0; k0 < 512; k0 += KT) {
    floatx4 pa = *(const floatx4*)(P + (long)(m0 + lm) * 512 + k0 + lk4);
    floatx4 wa = *(const floatx4*)(W1 + (long)(half * 512 + k0 + lkk) * 1024 + ccol + lc4);
    __syncthreads();
#pragma unroll
    for (int e = 0; e < 4; e++) at[lk4 + e][lm] = pa[e];
    *(floatx4*)&wt[lkk][lc4] = wa;
    __syncthreads();
#pragma unroll
    for (int kk = 0; kk < KT; kk++) {
      floatx4 av = *(const floatx4*)&at[kk][tm * 4];
      floatx4 wv = *(const floatx4*)&wt[kk][tn * 4];
#pragma unroll
      for (int mm = 0; mm < 4; mm++)
#pragma unroll
        for (int nn = 0; nn < 4; nn++)
          acc[mm][nn] += av[mm] * wv[nn];
    }
  }
#pragma unroll
  for (int mm = 0; mm < 4; mm++) {
    floatx4 o;
#pragma unroll
    for (int nn = 0; nn < 4; nn++) o[nn] = acc[mm][nn];
    *(floatx4*)(uv + (long)(m0 + tm * 4 + mm) * 2048 + c0 + tn * 4) = o;
  }
}

__global__ __launch_bounds__(256) void pair_valu(
    const float* __restrict__ uv, const float* __restrict__ W2,
    float* __restrict__ out, int mlp) {
  __shared__ float zt[KT][LSTRIDE];
  __shared__ float wt[KT][LSTRIDE];
  int bx = blockIdx.x;               // 4096 = 512 bi x 2 jh x 4 nb
  int nb = bx & 3;
  int jh = (bx >> 2) & 1;
  int bi = bx >> 3;
  int b = bi >> 7;
  int j0 = jh * 64;
  int n0 = nb * 64;
  int tid = threadIdx.x;
  int tm = tid >> 4, tn = tid & 15;
  int lj = tid >> 2;
  int lk4 = (tid & 3) * 4;
  int lkk = tid >> 4;
  int ln4 = (tid & 15) * 4;

  const float* urow = uv + (long)bi * 2048;
  const float* vrow = uv + (long)(b * 128 + j0 + lj) * 2048 + 1024;

  float acc[4][4] = {};

  for (int k0 = 0; k0 < 1024; k0 += KT) {
    floatx4 uu = *(const floatx4*)(urow + k0 + lk4);
    floatx4 vv = *(const floatx4*)(vrow + k0 + lk4);
    floatx4 wa = *(const floatx4*)(W2 + (long)(k0 + lkk) * 256 + n0 + ln4);
    __syncthreads();
#pragma unroll
    for (int e = 0; e < 4; e++) {
      float z = uu[e] + vv[e];
      zt[lk4 + e][lj] = z > 0.f ? z : 0.f;
    }
    *(floatx4*)&wt[lkk][ln4] = wa;
    __syncthreads();
#pragma unroll
    for (int kk = 0; kk < KT; kk++) {
      floatx4 zv = *(const floatx4*)&zt[kk][tm * 4];
      floatx4 wv = *(const floatx4*)&wt[kk][tn * 4];
#pragma unroll
      for (int mm = 0; mm < 4; mm++)
#pragma unroll
        for (int nn = 0; nn < 4; nn++)
          acc[mm][nn] += zv[mm] * wv[nn];
    }
  }
  float* ob = out + (long)(bi * 128 + j0) * 774 + mlp * 258 + n0 + tn * 4;
#pragma unroll
  for (int mm = 0; mm < 4; mm++) {
    float* orow = ob + (long)(tm * 4 + mm) * 774;
    floatx2 pa, pb;
    pa[0] = acc[mm][0] > 0.f ? acc[mm][0] : 0.f;
    pa[1] = acc[mm][1] > 0.f ? acc[mm][1] : 0.f;
    pb[0] = acc[mm][2] > 0.f ? acc[mm][2] : 0.f;
    pb[1] = acc[mm][3] > 0.f ? acc[mm][3] : 0.f;
    *(floatx2*)orow = pa;
    *(floatx2*)(orow + 2) = pb;
  }
}

__global__ __launch_bounds__(256) void head_kernel(
    const float* __restrict__ w3_0, const float* __restrict__ w3_1,
    const float* __restrict__ w3_2, float* out) {
  int wid = threadIdx.x >> 6, lane = threadIdx.x & 63;
  int r = blockIdx.x * 4 + wid;   // [0, 196608)
  int mlp = r >> 16;
  int row = r & 65535;
  const float* w3 = (mlp == 0) ? w3_0 : (mlp == 1) ? w3_1 : w3_2;
  const float* yp = out + (long)row * 774 + mlp * 258 + lane * 4;
  floatx2 ya = *(const floatx2*)yp;
  floatx2 yb = *(const floatx2*)(yp + 2);
  const float* wp = w3 + lane * 8;
  floatx4 wv0 = *(const floatx4*)wp;
  floatx4 wv1 = *(const floatx4*)(wp + 4);
  float s0 = ya[0] * wv0[0] + ya[1] * wv0[2] + yb[0] * wv1[0] + yb[1] * wv1[2];
  float s1 = ya[0] * wv0[1] + ya[1] * wv0[3] + yb[0] * wv1[1] + yb[1] * wv1[3];
#pragma unroll
  for (int off = 32; off > 0; off >>= 1) {
    s0 += __shfl_xor(s0, off, 64);
    s1 += __shfl_xor(s1, off, 64);
  }
  if (lane == 0) {
    float m = fmaxf(s0, s1);
    float e0 = __expf(s0 - m), e1 = __expf(s1 - m);
    float inv = 1.0f / (e0 + e1);
    floatx2 pr;
    pr[0] = e0 * inv;
    pr[1] = e1 * inv;
    *(floatx2*)(out + (long)row * 774 + mlp * 258 + 256) = pr;
  }
}

extern "C" void kernel_launch(void* const* d_in, const int* in_sizes, int n_in,
                              void* d_out, int out_size, void* d_ws, size_t ws_size,
                              hipStream_t stream) {
  const float* para = (const float*)d_in[0];
  const float* Wf1  = (const float*)d_in[1];
  const float* Wf2  = (const float*)d_in[2];
  const float* w3   = (const float*)d_in[3];
  const float* Wh1a = (const float*)d_in[4];
  const float* Wh1b = (const float*)d_in[5];
  const float* wl1  = (const float*)d_in[6];
  const float* Wh2a = (const float*)d_in[7];
  const float* Wh2b = (const float*)d_in[8];
  const float* wl2  = (const float*)d_in[9];

  float* outp = (float*)d_out;   // f32 [4*128*128][774]

  if (ws_size >= (size_t)27 * MB) {
    float* uF_all = (float*)d_ws;                                       // 6 MiB
    float* vF_all = (float*)((char*)d_ws + 6 * MB);                     // 6 MiB
    unsigned short* w2f_all = (unsigned short*)((char*)d_ws + 12 * MB); // 3 MiB
    unsigned short* w1f_all = (unsigned short*)((char*)d_ws + 15 * MB); // 12 MiB
    prep_all<<<1920, 256, 0, stream>>>(Wf1, Wh1a, Wh2a, Wf2, Wh1b, Wh2b,
                                       w1f_all, w2f_all);
    stage1_mfma3<<<1536, 256, 0, stream>>>(para, w1f_all, uF_all, vF_all);
    pair_mfma3<<<1536, 512, 0, stream>>>(uF_all, vF_all, w2f_all,
                                         w3, wl1, wl2, outp);
  } else {
    const float* W1s[3] = {Wf1, Wh1a, Wh2a};
    const float* W2s[3] = {Wf2, Wh1b, Wh2b};
    float* uv = (float*)d_ws;   // 4 MiB
    for (int mlp = 0; mlp < 3; mlp++) {
      stage1_valu<<<256, 256, 0, stream>>>(para, W1s[mlp], uv);
      pair_valu<<<4096, 256, 0, stream>>>(uv, W2s[mlp], outp, mlp);
    }
    head_kernel<<<49152, 256, 0, stream>>>(w3, wl1, wl2, outp);
  }
}

// Round 9
// 499.120 us; speedup vs baseline: 1.0331x; 1.0331x over previous
//
#include <hip/hip_runtime.h>

// PointerNet: B=4, N=128, H=512, d_pair=256.
// Interface (verified):
//   inputs  f32, setup_inputs dict order
//   d_out   f32, 50,724,864 elements = [4][128][128][774]
// Per mlp g in {future(Wf1,Wf2,w3), hist1(Wh1a,Wh1b,wl1), hist2(Wh2a,Wh2b,wl2)}:
//   uv[m][c'] = sum_h P[m][h] * W1[(c'>=1024?512:0)+h][c'&1023]     (m = b*128+i)
//   y[bi,j,n] = relu( sum_k relu(u[bi][k] + v[bj][k]) * W2[k][n] )
//   p = softmax_c( sum_n y[n] * w3[n][c] )
//   out[((bi)*128+j)*774 + g*258 + {n | 256+c}] = {y | p}
//
// R17 change (single lever; R16 post-mortem): R16 loaded v at the TOP of each
// body and consumed it ~15 insts later -> every body ate a ~300-500cyc L2
// stall, barrier-locked (MfmaUtil AND VALUBusy both fell to 27%). Reinstate
// R13's v REGISTER PREFETCH one kt ahead: frag_hi consumes current v regs,
// then the 8 loads for kt+1 issue BEFORE the MFMA cluster, so the L2 latency
// hides under ~2000 MFMA cycles and the barrier's vmcnt(0) drain finds them
// complete. kt=31 over-read lands in owned workspace (safe). Everything else
// (2-product zhi@{whi,wlo}, 64jx64n wave tile, stage1/prep/layouts) is
// UNCHANGED from R16.
//
// Workspace (fused tier, ws>=27MiB):
//   uF_all  f32 [3][512][1024]   6 MiB @0     (u half, row-major)
//   vF_all  f32 [3][524288]      6 MiB @6M    (v half, 32x32 fragment-major)
//   w2f_all u16 [3][524288]      3 MiB @12M   (32x32 B-frag layout, hi/lo)
//   w1f_all u16 [3][2M]         12 MiB @15M   (16x16 B-frag layout, stage1)
// Fallback (<27MiB): all-VALU path + head_kernel.

typedef __attribute__((ext_vector_type(4))) float floatx4;
typedef __attribute__((ext_vector_type(2))) float floatx2;
typedef __attribute__((ext_vector_type(16))) float floatx16;
typedef __attribute__((ext_vector_type(8))) short short8;

#define KT 16
#define LSTRIDE 68  // 64 + 4 pad (LDS bank-conflict break)
#define MB (1u << 20)

__device__ __forceinline__ void gload_lds16(const void* g, void* l) {
  __builtin_amdgcn_global_load_lds(
      (const __attribute__((address_space(1))) void*)g,
      (__attribute__((address_space(3))) void*)l, 16, 0, 0);
}

// Split 8 f32 into bf16 hi (truncated) + bf16 lo (exact remainder, truncated).
__device__ __forceinline__ void split8(const float* x, short8& hi, short8& lo) {
  unsigned hb[8], lb[8];
#pragma unroll
  for (int e = 0; e < 8; e++) {
    unsigned xb = __float_as_uint(x[e]);
    unsigned h = xb & 0xFFFF0000u;
    float l = x[e] - __uint_as_float(h);    // exact
    hb[e] = h;
    lb[e] = __float_as_uint(l) & 0xFFFF0000u;
  }
  union U { unsigned u[4]; short8 s; };
  U H, L;
#pragma unroll
  for (int p = 0; p < 4; p++) {
    H.u[p] = __builtin_amdgcn_perm(hb[2 * p + 1], hb[2 * p], 0x07060302u);
    L.u[p] = __builtin_amdgcn_perm(lb[2 * p + 1], lb[2 * p], 0x07060302u);
  }
  hi = H.s;
  lo = L.s;
}

// z = relu(u + v) for 8 k-slots, truncated-bf16 hi only (2-product scheme).
__device__ __forceinline__ short8 frag_hi(
    const floatx4& ua, const floatx4& ub,
    const floatx4& va, const floatx4& vb) {
  unsigned zb[8];
#pragma unroll
  for (int e = 0; e < 4; e++) {
    float z0 = fmaxf(ua[e] + va[e], 0.0f);
    float z1 = fmaxf(ub[e] + vb[e], 0.0f);
    zb[e] = __float_as_uint(z0);
    zb[4 + e] = __float_as_uint(z1);
  }
  union U { unsigned u[4]; short8 s; } H;
#pragma unroll
  for (int p = 0; p < 4; p++)
    H.u[p] = __builtin_amdgcn_perm(zb[2 * p + 1], zb[2 * p], 0x07060302u);
  return H.s;
}

// ---------------------------------------------------------------------------
// prep: W1 -> 16x16 B-frag layout (stage1);  W2 -> 32x32 B-frag layout (pair).
// W1F[kt(16)][NF(128)][hl(2)][lane(64)][e(8)]; lane = 16g + c holds
//   W1X[kt*32 + g*8 + e][NF*16 + c]  (u/v row split baked in).
// W2F[kt(32)][nf32(8)][hl(2)][ksub(2)][lane(64)][e(8)]; lane = 32g2 + c32
//   holds W2[kt*32 + ksub*16 + g2*8 + e][nf32*32 + c32].
// ---------------------------------------------------------------------------
__device__ __forceinline__ void prep_w1_body(
    int t, const float* __restrict__ W1, unsigned short* __restrict__ W1F) {
  int lane = t & 63;
  int nf = (t >> 6) & 127;
  int kt = t >> 13;                        // 0..15
  int g = lane >> 4, c = lane & 15;
  int n = nf * 16 + c;                     // 0..2047
  int kbase = kt * 32 + g * 8;
  const float* src = W1 + (long)((n >= 1024 ? 512 : 0) + kbase) * 1024 + (n & 1023);

  unsigned hb[8], lb[8];
#pragma unroll
  for (int e = 0; e < 8; e++) {
    float w = src[(long)e * 1024];
    unsigned wb = __float_as_uint(w);
    unsigned h = wb & 0xFFFF0000u;
    float l = w - __uint_as_float(h);
    hb[e] = h;
    lb[e] = __float_as_uint(l) & 0xFFFF0000u;
  }
  union U { unsigned u[4]; short8 s; };
  U H, L;
#pragma unroll
  for (int p = 0; p < 4; p++) {
    H.u[p] = __builtin_amdgcn_perm(hb[2 * p + 1], hb[2 * p], 0x07060302u);
    L.u[p] = __builtin_amdgcn_perm(lb[2 * p + 1], lb[2 * p], 0x07060302u);
  }
  long base = ((long)kt * 128 + nf) * 2 * 64 + lane;
  *(short8*)(W1F + (base + 0) * 8) = H.s;
  *(short8*)(W1F + (base + 64) * 8) = L.s;
}

__device__ __forceinline__ void prep_w2_body32(
    int t, const float* __restrict__ W2, unsigned short* __restrict__ W2F) {
  int lane = t & 63;
  int ksub = (t >> 6) & 1;
  int nf32 = (t >> 7) & 7;
  int kt = t >> 10;                        // 0..31
  int g2 = lane >> 5, c32 = lane & 31;
  int n = nf32 * 32 + c32;
  int kbase = kt * 32 + ksub * 16 + g2 * 8;

  unsigned hb[8], lb[8];
#pragma unroll
  for (int e = 0; e < 8; e++) {
    float w = W2[(long)(kbase + e) * 256 + n];
    unsigned wb = __float_as_uint(w);
    unsigned h = wb & 0xFFFF0000u;
    float l = w - __uint_as_float(h);
    hb[e] = h;
    lb[e] = __float_as_uint(l) & 0xFFFF0000u;
  }
  union U { unsigned u[4]; short8 s; };
  U H, L;
#pragma unroll
  for (int p = 0; p < 4; p++) {
    H.u[p] = __builtin_amdgcn_perm(hb[2 * p + 1], hb[2 * p], 0x07060302u);
    L.u[p] = __builtin_amdgcn_perm(lb[2 * p + 1], lb[2 * p], 0x07060302u);
  }
  // hl=0 at base, hl=1 at base + 2*64 lanes
  long base = ((((long)kt * 8 + nf32) * 2) * 2 + ksub) * 64 + lane;
  *(short8*)(W2F + (base + 0) * 8) = H.s;
  *(short8*)(W2F + (base + 128) * 8) = L.s;
}

// Fused prep: all 3 W1 (blocks 0..1535) + all 3 W2 (blocks 1536..1919).
__global__ __launch_bounds__(256) void prep_all(
    const float* __restrict__ Wf1, const float* __restrict__ Wh1a,
    const float* __restrict__ Wh2a, const float* __restrict__ Wf2,
    const float* __restrict__ Wh1b, const float* __restrict__ Wh2b,
    unsigned short* __restrict__ w1f_all, unsigned short* __restrict__ w2f_all) {
  int bx = blockIdx.x;
  if (bx < 1536) {
    int mlp = bx >> 9;
    const float* W1 = (mlp == 0) ? Wf1 : (mlp == 1) ? Wh1a : Wh2a;
    prep_w1_body((bx & 511) * 256 + threadIdx.x, W1,
                 w1f_all + (long)mlp * (2 * MB));   // 4 MiB = 2M shorts
  } else {
    int bb = bx - 1536;                             // 0..383
    int mlp = bb >> 7;
    const float* W2 = (mlp == 0) ? Wf2 : (mlp == 1) ? Wh1b : Wh2b;
    prep_w2_body32((bb & 127) * 256 + threadIdx.x, W2,
                   w2f_all + (long)mlp * (MB / 2)); // 1 MiB = 512K shorts
  }
}

// ---------------------------------------------------------------------------
// stage1 core: split-bf16 16x16x32 MFMA; writes uF (row-major) and vF
// (32x32 A-frag-major).  bx in [0,512) = 32 mblk(16 rows) x 16 nblk(128 n).
// vF flat: ((b*32+kt)*4 + jf32)*1024 + (kg*32 + (j&31))*16 + ksub*8 + e
//   holds v[b*128 + jf32*32 + (j&31)][kt*32 + ksub*16 + kg*8 + e].
// ---------------------------------------------------------------------------
__device__ __forceinline__ void stage1_core(
    int bx, const float* __restrict__ P,
    const unsigned short* __restrict__ W1F,
    float* __restrict__ uF, float* __restrict__ vF) {
  int m0 = (bx >> 4) * 16;
  int n0 = (bx & 15) * 128;
  int tid = threadIdx.x;
  int wid = tid >> 6, lane = tid & 63;
  int g = lane >> 4, r = lane & 15;
  int nw0 = n0 + wid * 32;                 // wave covers 2 n-frags

  const float* prow = P + (long)(m0 + r) * 512;

  floatx4 acc[2];
#pragma unroll
  for (int nf = 0; nf < 2; nf++) acc[nf] = (floatx4){0.f, 0.f, 0.f, 0.f};

  for (int kt = 0; kt < 16; kt++) {
    int k0 = kt * 32 + g * 8;
    float a[8];
    floatx4 a0 = *(const floatx4*)(prow + k0);
    floatx4 a1 = *(const floatx4*)(prow + k0 + 4);
#pragma unroll
    for (int e = 0; e < 4; e++) { a[e] = a0[e]; a[4 + e] = a1[e]; }
    short8 ahi, alo;
    split8(a, ahi, alo);
#pragma unroll
    for (int nf = 0; nf < 2; nf++) {
      int nfg = (nw0 >> 4) + nf;
      const unsigned short* wp = W1F + (((long)kt * 128 + nfg) * 2 * 64 + lane) * 8;
      short8 whi = *(const short8*)wp;
      short8 wlo = *(const short8*)(wp + 64 * 8);
      acc[nf] = __builtin_amdgcn_mfma_f32_16x16x32_bf16(ahi, whi, acc[nf], 0, 0, 0);
      acc[nf] = __builtin_amdgcn_mfma_f32_16x16x32_bf16(alo, whi, acc[nf], 0, 0, 0);
      acc[nf] = __builtin_amdgcn_mfma_f32_16x16x32_bf16(ahi, wlo, acc[nf], 0, 0, 0);
    }
  }
  // D: row = g*4 + reg (m within 16-tile), col = r (n within nf 16-tile)
  if (n0 < 1024) {
    // u half -> row-major uF[m][k]
#pragma unroll
    for (int nf = 0; nf < 2; nf++)
#pragma unroll
      for (int reg = 0; reg < 4; reg++)
        uF[(long)(m0 + g * 4 + reg) * 1024 + nw0 + nf * 16 + r] = acc[nf][reg];
  } else {
    // v half -> 32x32 fragment-major vF.  value = v[m][kt*32 + nf*16 + r]
    int kt = (nw0 - 1024) >> 5;            // wave-uniform
#pragma unroll
    for (int nf = 0; nf < 2; nf++) {
#pragma unroll
      for (int reg = 0; reg < 4; reg++) {
        int m = m0 + g * 4 + reg;
        int b = m >> 7;
        int jf = (m >> 5) & 3;
        long idx = (((long)(b * 32 + kt)) * 4 + jf) * 1024 +
                   ((r >> 3) * 32 + (m & 31)) * 16 + nf * 8 + (r & 7);
        vF[idx] = acc[nf][reg];
      }
    }
  }
}

__global__ __launch_bounds__(256) void stage1_mfma3(
    const float* __restrict__ P, const unsigned short* __restrict__ w1f_all,
    float* __restrict__ uF_all, float* __restrict__ vF_all) {
  int mlp = blockIdx.x >> 9;
  stage1_core(blockIdx.x & 511, P, w1f_all + (long)mlp * (2 * MB),
              uF_all + (long)mlp * 524288, vF_all + (long)mlp * 524288);
}

// ---------------------------------------------------------------------------
// pair kernel: 2-product 32x32x16 MFMA (zhi@whi + zhi@wlo).  512 thr = 8
// waves; wave (jh = wid>>2: 64 j rows = 2 m-tiles, nq = wid&3: 64 n = 2 nf).
// Per body: B gload_lds prefetch (kt+1) -> u LDS reads -> frag_hi from
// CURRENT v regs -> v register prefetch (kt+1) -> MFMA cluster -> barrier.
// The v/B loads get the whole MFMA cluster (~2000 cyc) before the barrier's
// vmcnt(0) drain.  Head fused.  acc[2][2] x f32x16 = 64 regs + 32 v regs.
// ---------------------------------------------------------------------------
#define PAIR_BODY(KTC, RBUF, SBUF)                                            \
  {                                                                           \
    const unsigned short* gs = W2F + (long)((KTC) + 1) * 16384;               \
    _Pragma("unroll")                                                         \
    for (int i = 0; i < 4; i++)                                               \
      gload_lds16(gs + (i * 512 + tid) * 8, &(SBUF)[(i * 512 + tid) * 8]);    \
    floatx4 u0 = *(const floatx4*)&ulds[(KTC) * 32 + g2 * 8];                 \
    floatx4 u1 = *(const floatx4*)&ulds[(KTC) * 32 + g2 * 8 + 4];             \
    floatx4 u2 = *(const floatx4*)&ulds[(KTC) * 32 + 16 + g2 * 8];            \
    floatx4 u3 = *(const floatx4*)&ulds[(KTC) * 32 + 16 + g2 * 8 + 4];        \
    short8 a00 = frag_hi(u0, u1, va0, va1);   /* m-tile 0, ksub 0 */          \
    short8 a01 = frag_hi(u2, u3, va2, va3);   /* m-tile 0, ksub 1 */          \
    short8 a10 = frag_hi(u0, u1, vb0, vb1);   /* m-tile 1, ksub 0 */          \
    short8 a11 = frag_hi(u2, u3, vb2, vb3);   /* m-tile 1, ksub 1 */          \
    {                                                                         \
      const float* vp0 = vbase0 + (long)((KTC) + 1) * 4096;                   \
      const float* vp1 = vbase1 + (long)((KTC) + 1) * 4096;                   \
      va0 = *(const floatx4*)(vp0);                                           \
      va1 = *(const floatx4*)(vp0 + 4);                                       \
      va2 = *(const floatx4*)(vp0 + 8);                                       \
      va3 = *(const floatx4*)(vp0 + 12);                                      \
      vb0 = *(const floatx4*)(vp1);                                           \
      vb1 = *(const floatx4*)(vp1 + 4);                                       \
      vb2 = *(const floatx4*)(vp1 + 8);                                       \
      vb3 = *(const floatx4*)(vp1 + 12);                                      \
    }                                                                         \
    __builtin_amdgcn_s_setprio(1);                                            \
    _Pragma("unroll")                                                         \
    for (int nf = 0; nf < 2; nf++) {                                          \
      const unsigned short* wp = (RBUF) + ((nq * 2 + nf) * 4) * 512 + lane * 8; \
      short8 whi0 = *(const short8*)wp;                                       \
      short8 whi1 = *(const short8*)(wp + 512);                               \
      short8 wlo0 = *(const short8*)(wp + 1024);                              \
      short8 wlo1 = *(const short8*)(wp + 1536);                              \
      acc[0][nf] = __builtin_amdgcn_mfma_f32_32x32x16_bf16(a00, whi0, acc[0][nf], 0, 0, 0); \
      acc[1][nf] = __builtin_amdgcn_mfma_f32_32x32x16_bf16(a10, whi0, acc[1][nf], 0, 0, 0); \
      acc[0][nf] = __builtin_amdgcn_mfma_f32_32x32x16_bf16(a01, whi1, acc[0][nf], 0, 0, 0); \
      acc[1][nf] = __builtin_amdgcn_mfma_f32_32x32x16_bf16(a11, whi1, acc[1][nf], 0, 0, 0); \
      acc[0][nf] = __builtin_amdgcn_mfma_f32_32x32x16_bf16(a00, wlo0, acc[0][nf], 0, 0, 0); \
      acc[1][nf] = __builtin_amdgcn_mfma_f32_32x32x16_bf16(a10, wlo0, acc[1][nf], 0, 0, 0); \
      acc[0][nf] = __builtin_amdgcn_mfma_f32_32x32x16_bf16(a01, wlo1, acc[0][nf], 0, 0, 0); \
      acc[1][nf] = __builtin_amdgcn_mfma_f32_32x32x16_bf16(a11, wlo1, acc[1][nf], 0, 0, 0); \
    }                                                                         \
    __builtin_amdgcn_s_setprio(0);                                            \
    __syncthreads();                                                          \
  }

__global__ __launch_bounds__(512, 4) void pair_mfma3(
    const float* __restrict__ uF_all, const float* __restrict__ vF_all,
    const unsigned short* __restrict__ w2f_all,
    const float* __restrict__ w3_0, const float* __restrict__ w3_1,
    const float* __restrict__ w3_2, float* __restrict__ out) {
  __shared__ unsigned short wbuf[2][16384];   // 2 x 32 KB B double buffer
  __shared__ float ulds[1024];                // u row (4 KB); ps scratch later
  int orig = blockIdx.x;                      // 1536 = 8 XCD * 192
  int id = (orig & 7) * 192 + (orig >> 3);    // bijective XCD swizzle
  int mlp = id >> 9;
  int bi = id & 511;
  int b = bi >> 7;
  const float* w3 = (mlp == 0) ? w3_0 : (mlp == 1) ? w3_1 : w3_2;
  const float* uF = uF_all + (long)mlp * 524288;
  const float* vF = vF_all + (long)mlp * 524288;
  const unsigned short* W2F = w2f_all + (long)mlp * 524288;

  int tid = threadIdx.x;
  int wid = tid >> 6;           // 0..7
  int lane = tid & 63;
  int jh = wid >> 2;            // j-half: rows [jh*64, +64) = m-tiles jh*2, jh*2+1
  int nq = wid & 3;             // n-quarter: cols [nq*64, +64) = nf32 nq*2, nq*2+1
  int g2 = lane >> 5;           // k-group within frag
  int c32 = lane & 31;          // row (A) / col (B/D) within 32-tile

  // v bases for the two m-tiles (jf = jh*2 + mm); per-kt stride 4096 floats.
  const float* vbase0 = vF + ((long)b * 128 + jh * 2 + 0) * 1024 + lane * 16;
  const float* vbase1 = vF + ((long)b * 128 + jh * 2 + 1) * 1024 + lane * 16;

  // Prologue: stage u row (4KB) + B slice kt=0; load v regs kt=0.
  const float* urow = uF + (long)bi * 1024;
  if (tid < 256) gload_lds16(urow + tid * 4, &ulds[tid * 4]);
#pragma unroll
  for (int i = 0; i < 4; i++)
    gload_lds16(W2F + (i * 512 + tid) * 8, &wbuf[0][(i * 512 + tid) * 8]);
  floatx4 va0 = *(const floatx4*)(vbase0);
  floatx4 va1 = *(const floatx4*)(vbase0 + 4);
  floatx4 va2 = *(const floatx4*)(vbase0 + 8);
  floatx4 va3 = *(const floatx4*)(vbase0 + 12);
  floatx4 vb0 = *(const floatx4*)(vbase1);
  floatx4 vb1 = *(const floatx4*)(vbase1 + 4);
  floatx4 vb2 = *(const floatx4*)(vbase1 + 8);
  floatx4 vb3 = *(const floatx4*)(vbase1 + 12);

  floatx16 acc[2][2];
#pragma unroll
  for (int mm = 0; mm < 2; mm++)
#pragma unroll
    for (int nf = 0; nf < 2; nf++)
#pragma unroll
      for (int e = 0; e < 16; e++) acc[mm][nf][e] = 0.f;

  __syncthreads();   // u + B slice 0 resident

  for (int kt = 0; kt < 32; kt += 2) {
    PAIR_BODY(kt, wbuf[1] - 16384, wbuf[1]);        // read buf0, stage buf1
    PAIR_BODY(kt + 1, wbuf[1], wbuf[1] - 16384);    // read buf1, stage buf0
  }

  // Epilogue: D col = c32 (n), row = (reg&3) + 8*(reg>>2) + 4*g2 (j within
  // 32-tile).  y stores + fused head: reduce over c32, psum via ulds scratch.
  float* ps = ulds;   // 128 rows x 4 nq x 2 = 1024 floats (u data dead)
  float* ob = out + (long)(bi * 128) * 774 + mlp * 258;
  floatx2 w3v[2];
#pragma unroll
  for (int nf = 0; nf < 2; nf++)
    w3v[nf] = *(const floatx2*)(w3 + (nq * 64 + nf * 32 + c32) * 2);
#pragma unroll
  for (int mm = 0; mm < 2; mm++) {
#pragma unroll
    for (int reg = 0; reg < 16; reg++) {
      int row = jh * 64 + mm * 32 + (reg & 3) + 8 * (reg >> 2) + 4 * g2;
      float* orow = ob + (long)row * 774 + nq * 64 + c32;
      float s0 = 0.f, s1 = 0.f;
#pragma unroll
      for (int nf = 0; nf < 2; nf++) {
        float y = acc[mm][nf][reg];
        y = y > 0.f ? y : 0.f;
        orow[nf * 32] = y;
        s0 += y * w3v[nf][0];
        s1 += y * w3v[nf][1];
      }
#pragma unroll
      for (int off = 1; off < 32; off <<= 1) {
        s0 += __shfl_xor(s0, off, 64);
        s1 += __shfl_xor(s1, off, 64);
      }
      if (c32 == 0) {
        ps[row * 8 + nq * 2 + 0] = s0;
        ps[row * 8 + nq * 2 + 1] = s1;
      }
    }
  }
  __syncthreads();
  if (tid < 128) {
    int row = tid;
    float s0 = ps[row * 8 + 0] + ps[row * 8 + 2] + ps[row * 8 + 4] + ps[row * 8 + 6];
    float s1 = ps[row * 8 + 1] + ps[row * 8 + 3] + ps[row * 8 + 5] + ps[row * 8 + 7];
    float m = fmaxf(s0, s1);
    float e0 = __expf(s0 - m), e1 = __expf(s1 - m);
    float inv = 1.0f / (e0 + e1);
    floatx2 pr;
    pr[0] = e0 * inv;
    pr[1] = e1 * inv;
    *(floatx2*)(ob + (long)row * 774 + 256) = pr;   // 8B aligned
  }
}

// ---------------------------------------------------------------------------
// VALU fallback path (proven; used only if ws < 27 MiB). uv row-major 4 MiB.
// ---------------------------------------------------------------------------
__global__ __launch_bounds__(256) void stage1_valu(
    const float* __restrict__ P, const float* __restrict__ W1,
    float* __restrict__ uv) {
  __shared__ float at[KT][LSTRIDE];
  __shared__ float wt[KT][LSTRIDE];
  int bx = blockIdx.x;
  int m0 = (bx >> 5) * 64;
  int c0 = (bx & 31) * 64;
  int half = c0 >> 10;
  int ccol = c0 & 1023;
  int tid = threadIdx.x;
  int tm = tid >> 4, tn = tid & 15;
  int lm = tid >> 2;
  int lk4 = (tid & 3) * 4;
  int lkk = tid >> 4;
  int lc4 = (tid & 15) * 4;

  float acc[4][4] = {};

  for (int k0 = 0; k0 < 512; k0 += KT) {
    floatx4 pa = *(const floatx4*)(P + (long)(m0 + lm) * 512 + k0 + lk4);
    floatx4 wa = *(const floatx4*)(W1 + (long)(half * 512 + k0 + lkk) * 1024 + ccol + lc4);
    __syncthreads();
#pragma unroll
    for (int e = 0; e < 4; e++) at[lk4 + e][lm] = pa[e];
    *(floatx4*)&wt[lkk][lc4] = wa;
    __syncthreads();
#pragma unroll
    for (int kk = 0; kk < KT; kk++) {
      floatx4 av = *(const floatx4*)&at[kk][tm * 4];
      floatx4 wv = *(const floatx4*)&wt[kk][tn * 4];
#pragma unroll
      for (int mm = 0; mm < 4; mm++)
#pragma unroll
        for (int nn = 0; nn < 4; nn++)
          acc[mm][nn] += av[mm] * wv[nn];
    }
  }
#pragma unroll
  for (int mm = 0; mm < 4; mm++) {
    floatx4 o;
#pragma unroll
    for (int nn = 0; nn < 4; nn++) o[nn] = acc[mm][nn];
    *(floatx4*)(uv + (long)(m0 + tm * 4 + mm) * 2048 + c0 + tn * 4) = o;
  }
}

__global__ __launch_bounds__(256) void pair_valu(
    const float* __restrict__ uv, const float* __restrict__ W2,
    float* __restrict__ out, int mlp) {
  __shared__ float zt[KT][LSTRIDE];
  __shared__ float wt[KT][LSTRIDE];
  int bx = blockIdx.x;               // 4096 = 512 bi x 2 jh x 4 nb
  int nb = bx & 3;
  int jh = (bx >> 2) & 1;
  int bi = bx >> 3;
  int b = bi >> 7;
  int j0 = jh * 64;
  int n0 = nb * 64;
  int tid = threadIdx.x;
  int tm = tid >> 4, tn = tid & 15;
  int lj = tid >> 2;
  int lk4 = (tid & 3) * 4;
  int lkk = tid >> 4;
  int ln4 = (tid & 15) * 4;

  const float* urow = uv + (long)bi * 2048;
  const float* vrow = uv + (long)(b * 128 + j0 + lj) * 2048 + 1024;

  float acc[4][4] = {};

  for (int k0 = 0; k0 < 1024; k0 += KT) {
    floatx4 uu = *(const floatx4*)(urow + k0 + lk4);
    floatx4 vv = *(const floatx4*)(vrow + k0 + lk4);
    floatx4 wa = *(const floatx4*)(W2 + (long)(k0 + lkk) * 256 + n0 + ln4);
    __syncthreads();
#pragma unroll
    for (int e = 0; e < 4; e++) {
      float z = uu[e] + vv[e];
      zt[lk4 + e][lj] = z > 0.f ? z : 0.f;
    }
    *(floatx4*)&wt[lkk][ln4] = wa;
    __syncthreads();
#pragma unroll
    for (int kk = 0; kk < KT; kk++) {
      floatx4 zv = *(const floatx4*)&zt[kk][tm * 4];
      floatx4 wv = *(const floatx4*)&wt[kk][tn * 4];
#pragma unroll
      for (int mm = 0; mm < 4; mm++)
#pragma unroll
        for (int nn = 0; nn < 4; nn++)
          acc[mm][nn] += zv[mm] * wv[nn];
    }
  }
  float* ob = out + (long)(bi * 128 + j0) * 774 + mlp * 258 + n0 + tn * 4;
#pragma unroll
  for (int mm = 0; mm < 4; mm++) {
    float* orow = ob + (long)(tm * 4 + mm) * 774;
    floatx2 pa, pb;
    pa[0] = acc[mm][0] > 0.f ? acc[mm][0] : 0.f;
    pa[1] = acc[mm][1] > 0.f ? acc[mm][1] : 0.f;
    pb[0] = acc[mm][2] > 0.f ? acc[mm][2] : 0.f;
    pb[1] = acc[mm][3] > 0.f ? acc[mm][3] : 0.f;
    *(floatx2*)orow = pa;
    *(floatx2*)(orow + 2) = pb;
  }
}

__global__ __launch_bounds__(256) void head_kernel(
    const float* __restrict__ w3_0, const float* __restrict__ w3_1,
    const float* __restrict__ w3_2, float* out) {
  int wid = threadIdx.x >> 6, lane = threadIdx.x & 63;
  int r = blockIdx.x * 4 + wid;   // [0, 196608)
  int mlp = r >> 16;
  int row = r & 65535;
  const float* w3 = (mlp == 0) ? w3_0 : (mlp == 1) ? w3_1 : w3_2;
  const float* yp = out + (long)row * 774 + mlp * 258 + lane * 4;
  floatx2 ya = *(const floatx2*)yp;
  floatx2 yb = *(const floatx2*)(yp + 2);
  const float* wp = w3 + lane * 8;
  floatx4 wv0 = *(const floatx4*)wp;
  floatx4 wv1 = *(const floatx4*)(wp + 4);
  float s0 = ya[0] * wv0[0] + ya[1] * wv0[2] + yb[0] * wv1[0] + yb[1] * wv1[2];
  float s1 = ya[0] * wv0[1] + ya[1] * wv0[3] + yb[0] * wv1[1] + yb[1] * wv1[3];
#pragma unroll
  for (int off = 32; off > 0; off >>= 1) {
    s0 += __shfl_xor(s0, off, 64);
    s1 += __shfl_xor(s1, off, 64);
  }
  if (lane == 0) {
    float m = fmaxf(s0, s1);
    float e0 = __expf(s0 - m), e1 = __expf(s1 - m);
    float inv = 1.0f / (e0 + e1);
    floatx2 pr;
    pr[0] = e0 * inv;
    pr[1] = e1 * inv;
    *(floatx2*)(out + (long)row * 774 + mlp * 258 + 256) = pr;
  }
}

extern "C" void kernel_launch(void* const* d_in, const int* in_sizes, int n_in,
                              void* d_out, int out_size, void* d_ws, size_t ws_size,
                              hipStream_t stream) {
  const float* para = (const float*)d_in[0];
  const float* Wf1  = (const float*)d_in[1];
  const float* Wf2  = (const float*)d_in[2];
  const float* w3   = (const float*)d_in[3];
  const float* Wh1a = (const float*)d_in[4];
  const float* Wh1b = (const float*)d_in[5];
  const float* wl1  = (const float*)d_in[6];
  const float* Wh2a = (const float*)d_in[7];
  const float* Wh2b = (const float*)d_in[8];
  const float* wl2  = (const float*)d_in[9];

  float* outp = (float*)d_out;   // f32 [4*128*128][774]

  if (ws_size >= (size_t)27 * MB) {
    float* uF_all = (float*)d_ws;                                       // 6 MiB
    float* vF_all = (float*)((char*)d_ws + 6 * MB);                     // 6 MiB
    unsigned short* w2f_all = (unsigned short*)((char*)d_ws + 12 * MB); // 3 MiB
    unsigned short* w1f_all = (unsigned short*)((char*)d_ws + 15 * MB); // 12 MiB
    prep_all<<<1920, 256, 0, stream>>>(Wf1, Wh1a, Wh2a, Wf2, Wh1b, Wh2b,
                                       w1f_all, w2f_all);
    stage1_mfma3<<<1536, 256, 0, stream>>>(para, w1f_all, uF_all, vF_all);
    pair_mfma3<<<1536, 512, 0, stream>>>(uF_all, vF_all, w2f_all,
                                         w3, wl1, wl2, outp);
  } else {
    const float* W1s[3] = {Wf1, Wh1a, Wh2a};
    const float* W2s[3] = {Wf2, Wh1b, Wh2b};
    float* uv = (float*)d_ws;   // 4 MiB
    for (int mlp = 0; mlp < 3; mlp++) {
      stage1_valu<<<256, 256, 0, stream>>>(para, W1s[mlp], uv);
      pair_valu<<<4096, 256, 0, stream>>>(uv, W2s[mlp], outp, mlp);
    }
    head_kernel<<<49152, 256, 0, stream>>>(w3, wl1, wl2, outp);
  }
}